// Round 12
// baseline (271.869 us; speedup 1.0000x reference)
//
#include <hip/hip_runtime.h>
#include <math.h>

// ---------------------------------------------------------------------------
// CSDM pipeline on MI355X. fp32 in/out, fp32/bf16 intermediates in d_ws.
// B=4, C=32, H=W=256. MFMA head conv; bf16 channel-last gather sources;
// channel means fused into producer kernels (no mean pass).
// Layout law (r6): bulk WRITES plane-major dense; gather READS channel-last.
// r7: head kernel split per-head across blockIdx.z (2048 blocks), LDS union.
// r8/r11 EMPIRICAL LAW: hipcc VGPR cap for __launch_bounds__(256,N) ~256/N
// ((256,3)->84, (256,4)->64, (256,5)->51, (256,6)->40, (256,7)->36).
// Raising N is safe ONLY when natural VGPR <= cap; else scratch spill
// (matched FETCH+WRITE jump). ds_all natural 36 -> N=6 OK (r15).
// r9: all three ds levels in ONE launch. r10: pw+qproj MFMA-ized.
// r12: cross-run variance on latency-bound kernels is +/-15-30%; only
// same-run comparisons are interpretable. ~125us of dur_us is constant
// harness overhead; kernel-time budget is ~140us.
// r13: deform gathers LDS-staged (tanh-bounded 14x14/10x10 windows).
// r14: window points 80B stride; gate fused into final.
// r15: ds_all (256,6) + s1 restored. 264.7 = champion.
// r16 FAILED+REVERTED: slot-XOR swizzle + pk-fma + addressing at VGPR=64
// cap -> conflicts up AND spill. Lesson: at VGPR==cap, added per-access
// addressing => spill; bundles are unattributable.
// r17: gather 2x8 split enabling (256,5): VGPR 48, no spill; neutral perf
// (occupancy not the binder). Kept for the 3-reg headroom.
// r18: pk-math ISOLATED: gather accumulators as v2f -> v_pk_fma_f32
// (256 pk vs 512 scalar FMA/thread), plain addressing, same reg count,
// bit-identical per-channel order. Tripwire: FETCH/WRITE jump -> revert.
// ---------------------------------------------------------------------------

constexpr int B = 4, C = 32, H = 256, W = 256;
constexpr int HW = H * W;
constexpr int H1 = 128, W1 = 128, HW1 = H1 * W1;
constexpr int H2 = 64,  W2 = 64,  HW2 = H2 * W2;
constexpr int CH = 16;   // head hidden channels
constexpr int CO = 12;   // head output channels
constexpr int TILE = 16;
constexpr int HALO = 18;
constexpr int TAREA = HALO * HALO;   // 324
constexpr int WP = 258;              // padded q edge
constexpr int PSTR = 40;             // zwin point stride in halfwords (80 B)

typedef unsigned short ushort_t;
typedef __attribute__((ext_vector_type(8))) short bf16x8;
typedef __attribute__((ext_vector_type(4))) float f32x4;
typedef __attribute__((ext_vector_type(2))) float v2f;

static __device__ __forceinline__ float fast_rcp(float x) { return __builtin_amdgcn_rcpf(x); }
static __device__ __forceinline__ float silu_f(float x) { return x * fast_rcp(1.0f + __expf(-x)); }
static __device__ __forceinline__ float tanh_f(float x) {
    float xc = fminf(fmaxf(x, -15.0f), 15.0f);
    float e = __expf(2.0f * xc);
    return (e - 1.0f) * fast_rcp(e + 1.0f);
}
static __device__ __forceinline__ ushort_t f2b(float f) {   // fp32 -> bf16 RNE
    unsigned u = __float_as_uint(f);
    return (ushort_t)((u + 0x7fffu + ((u >> 16) & 1u)) >> 16);
}
static __device__ __forceinline__ float bl(unsigned u) { return __uint_as_float(u << 16); }
static __device__ __forceinline__ float bh(unsigned u) { return __uint_as_float(u & 0xffff0000u); }

// Multi-value butterfly: 8 per-thread channel values -> full-wave sum of
// channel c(lane)=4*b0+2*b1+b2 in lane. 10 shuffles vs 48 for 8 wave_sums.
static __device__ __forceinline__ float red8_ch(float v0, float v1, float v2, float v3,
                                                float v4, float v5, float v6, float v7,
                                                int lane) {
    bool q0 = (lane & 1) != 0, q1 = (lane & 2) != 0, q2 = (lane & 4) != 0;
    float a0 = (q0 ? v4 : v0) + __shfl_xor(q0 ? v0 : v4, 1, 64);
    float a1 = (q0 ? v5 : v1) + __shfl_xor(q0 ? v1 : v5, 1, 64);
    float a2 = (q0 ? v6 : v2) + __shfl_xor(q0 ? v2 : v6, 1, 64);
    float a3 = (q0 ? v7 : v3) + __shfl_xor(q0 ? v3 : v7, 1, 64);
    float c0 = (q1 ? a2 : a0) + __shfl_xor(q1 ? a0 : a2, 2, 64);
    float c1 = (q1 ? a3 : a1) + __shfl_xor(q1 ? a1 : a3, 2, 64);
    float e  = (q2 ? c1 : c0) + __shfl_xor(q2 ? c0 : c1, 4, 64);
    e += __shfl_xor(e, 8, 64);
    e += __shfl_xor(e, 16, 64);
    e += __shfl_xor(e, 32, 64);
    return e;
}

// ---- pre: pool2 (x->s1) + qpad border + dall zero + weight reorders -------
__global__ void pre_kernel(const float* __restrict__ x, float* __restrict__ s1,
                           ushort_t* __restrict__ qpad, float* __restrict__ dall,
                           const float* __restrict__ h1w1, const float* __restrict__ h2w1,
                           ushort_t* __restrict__ w1ra, ushort_t* __restrict__ w1rb,
                           const float* __restrict__ pw0, const float* __restrict__ pw1,
                           const float* __restrict__ pw2, const float* __restrict__ qw,
                           ushort_t* __restrict__ pwr) {
    int idx = blockIdx.x * blockDim.x + threadIdx.x;
    constexpr int NP = B * C * HW1;
    if (idx < NP) {
        int wo = idx % W1; int t = idx / W1;
        int ho = t % H1;   t /= H1;
        const float* src = x + ((size_t)t * H + (size_t)ho * 2) * W + (size_t)wo * 2;
        s1[idx] = (src[0] + src[1] + src[W] + src[W + 1]) * 0.25f;
        return;
    }
    int i = idx - NP;
    if (i < 4112) {                       // qpad border (4*1028)
        int b = i / 1028, r = i % 1028;
        int y, xx;
        if (r < 258)      { y = 0;           xx = r; }
        else if (r < 516) { y = 257;         xx = r - 258; }
        else if (r < 772) { y = r - 516 + 1; xx = 0; }
        else              { y = r - 772 + 1; xx = 257; }
        uint4 z4 = {0, 0, 0, 0};
        uint4* p = (uint4*)(qpad + (((size_t)b * WP + y) * WP + xx) * 32);
        p[0] = z4; p[1] = z4; p[2] = z4; p[3] = z4;
        return;
    }
    i -= 4112;
    if (i < 512) { dall[i] = 0.0f; return; }
    i -= 512;
    if (i < 4608) {                       // w1ra[o*288 + tap*32 + ci]
        int o = i / 288, k = i - o * 288;
        int j = k >> 5, ci = k & 31;
        w1ra[i] = f2b(h1w1[(o * C + ci) * 9 + j]);
        return;
    }
    i -= 4608;
    if (i < 4608) {
        int o = i / 288, k = i - o * 288;
        int j = k >> 5, ci = k & 31;
        w1rb[i] = f2b(h2w1[(o * C + ci) * 9 + j]);
        return;
    }
    i -= 4608;
    if (i < 4096) {                       // pwr[m][och][inch] bf16 row-major
        int mm = i >> 10, k = i & 1023;
        int o = k >> 5, ci = k & 31;
        const float* wsrc = (mm == 0) ? pw0 : (mm == 1) ? pw1 : (mm == 2) ? pw2 : qw;
        pwr[i] = f2b(wsrc[o * C + ci]);
    }
}

// ---- fused ds_block, all 3 levels in one launch, MFMA pointwise -----------
// blockIdx.x: [0,1024) level0 (z0+qproj+means, reads x), [1024,1280) level1
// (z1cl, reads s1), [1280,1344) level2 (z2cl, pools 2x2 from s1).
struct DsParams {
    const float* dw;
    const float* g;  const float* b;  const float* m; const float* v;
};

// launch_bounds (256,6): natural VGPR=36 <= cap(6)=40 -> no spill; LDS
// 6x23040=138KB -> 6 blocks/CU; grid 1344 <= 1536 fully resident.
__global__ __launch_bounds__(256, 6) void fused_ds_all_kernel(
        const float* __restrict__ x, const float* __restrict__ s1,
        DsParams P0, DsParams P1, DsParams P2, const ushort_t* __restrict__ pwr,
        float* __restrict__ z0out, ushort_t* __restrict__ z1cl,
        ushort_t* __restrict__ z2cl, ushort_t* __restrict__ qout,
        float* __restrict__ dall) {
    // tileu (20736 B) and bstg (256 px * 40 ch bf16 = 20480 B) share space.
    __shared__ __align__(16) char smem[16 * TAREA * 4];
    unsigned* tileu = (unsigned*)smem;
    ushort_t* bstg  = (ushort_t*)smem;
    __shared__ v2f dwp[16 * 9];
    __shared__ __align__(16) float sc[32], sh[32];
    __shared__ float zsum[4][32];

    int bx = blockIdx.x;
    int level = (bx < 1024) ? 0 : (bx < 1280 ? 1 : 2);
    int rel = bx - ((level == 0) ? 0 : (level == 1 ? 1024 : 1280));
    int Hs = (level == 0) ? H : (level == 1 ? H1 : H2);
    int Ws = Hs;
    int tilesX = Ws / TILE;
    int tilesT = tilesX * (Hs / TILE);
    int b = rel / tilesT;
    int tile = rel - b * tilesT;
    int ox = (tile % tilesX) * TILE;
    int oy = (tile / tilesX) * TILE;
    DsParams P = (level == 0) ? P0 : (level == 1 ? P1 : P2);
    int HWs = Hs * Ws;
    int tid = threadIdx.x;
    int lane = tid & 63, wv = tid >> 6;
    int n15 = lane & 15, quad = lane >> 4;
    int tx = tid & 15, ty = tid >> 4;

    for (int i = tid; i < 16 * 9; i += 256) {
        int c2 = i / 9, j = i - c2 * 9;
        dwp[i] = (v2f){P.dw[(2 * c2) * 9 + j], P.dw[(2 * c2 + 1) * 9 + j]};
    }
    if (tid < 32) {
        float s0 = P.g[tid] * rsqrtf(P.v[tid] + 1e-5f);
        sc[tid] = s0;
        sh[tid] = P.b[tid] - P.m[tid] * s0;
    }
    const float* xb = x + (size_t)b * C * HW;
    const float* s1b = s1 + (size_t)b * C * HW1;
    for (int i = tid; i < 16 * TAREA; i += 256) {
        int c2 = i / TAREA, r = i - c2 * TAREA;
        int yy = r / HALO, xx = r - yy * HALO;
        int gy = oy - 1 + yy, gx = ox - 1 + xx;
        float v0 = 0.0f, v1 = 0.0f;
        if (gy >= 0 && gy < Hs && gx >= 0 && gx < Ws) {
            if (level == 0) {
                const float* sp = xb + (size_t)(2 * c2) * HW + (size_t)gy * W + gx;
                v0 = sp[0]; v1 = sp[HW];
            } else if (level == 1) {
                const float* sp = s1b + (size_t)(2 * c2) * HW1 + (size_t)gy * W1 + gx;
                v0 = sp[0]; v1 = sp[HW1];
            } else {
                // s2 = 2x2 mean of s1 (old pool4_kernel numerics)
                const float* sp = s1b + (size_t)(2 * c2) * HW1 + (size_t)(gy * 2) * W1 + gx * 2;
                v0 = (sp[0] + sp[1] + sp[W1] + sp[W1 + 1]) * 0.25f;
                sp += HW1;
                v1 = (sp[0] + sp[1] + sp[W1] + sp[W1 + 1]) * 0.25f;
            }
        }
        tileu[i] = (unsigned)f2b(v0) | ((unsigned)f2b(v1) << 16);
    }
    __syncthreads();

    // ---- depthwise conv (VALU; per-channel, not matmul-shaped) ----
    int off[9];
#pragma unroll
    for (int jy = 0; jy < 3; ++jy)
#pragma unroll
        for (int jx = 0; jx < 3; ++jx)
            off[jy * 3 + jx] = (ty + jy) * HALO + tx + jx;

    v2f t2[16];
#pragma unroll
    for (int c2 = 0; c2 < 16; ++c2) {
        v2f s = {0.0f, 0.0f};
        const unsigned* tp = tileu + c2 * TAREA;
#pragma unroll
        for (int j = 0; j < 9; ++j) {
            unsigned u = tp[off[j]];
            v2f val = {bl(u), bh(u)};
            s += dwp[c2 * 9 + j] * val;
        }
        t2[c2] = s;
    }
    __syncthreads();   // all dwconv tileu reads done; bstg may overwrite

    // ---- stage dwconv out as bf16 [px][40ch] (pad 40 -> 2-way banks) ----
    {
        unsigned up[16];
#pragma unroll
        for (int j = 0; j < 16; ++j)
            up[j] = (unsigned)f2b(t2[j].x) | ((unsigned)f2b(t2[j].y) << 16);
        uint4* bw = (uint4*)(bstg + (size_t)tid * 40);
#pragma unroll
        for (int j = 0; j < 4; ++j)
            bw[j] = make_uint4(up[4 * j], up[4 * j + 1], up[4 * j + 2], up[4 * j + 3]);
    }
    __syncthreads();

    // ---- MFMA pointwise: A = weights [och 16][inch 32], B = [inch 32][px 16]
    const ushort_t* pwl = pwr + level * 1024;
    bf16x8 apw0 = *(const bf16x8*)(pwl + n15 * 32 + quad * 8);
    bf16x8 apw1 = *(const bf16x8*)(pwl + (16 + n15) * 32 + quad * 8);
    f32x4 c1[4][2];
#pragma unroll
    for (int g4 = 0; g4 < 4; ++g4) {
        bf16x8 bf = *(const bf16x8*)(bstg + ((wv * 4 + g4) * 16 + n15) * 40 + quad * 8);
        f32x4 z = {0.0f, 0.0f, 0.0f, 0.0f};
        c1[g4][0] = __builtin_amdgcn_mfma_f32_16x16x32_bf16(apw0, bf, z, 0, 0, 0);
        c1[g4][1] = __builtin_amdgcn_mfma_f32_16x16x32_bf16(apw1, bf, z, 0, 0, 0);
    }
    // BN + SiLU on C-frags: och = 16*t + 4*quad + r, px = n15 of row wv*4+g4
    f32x4 sc0 = *(const f32x4*)(sc + 4 * quad);
    f32x4 sc1 = *(const f32x4*)(sc + 16 + 4 * quad);
    f32x4 sh0 = *(const f32x4*)(sh + 4 * quad);
    f32x4 sh1 = *(const f32x4*)(sh + 16 + 4 * quad);
#pragma unroll
    for (int g4 = 0; g4 < 4; ++g4)
#pragma unroll
        for (int r = 0; r < 4; ++r) {
            c1[g4][0][r] = silu_f(c1[g4][0][r] * sc0[r] + sh0[r]);
            c1[g4][1][r] = silu_f(c1[g4][1][r] * sc1[r] + sh1[r]);
        }
    __syncthreads();   // all MFMA1 B reads done; overwrite bstg with silu'd

    // silu'd bf16 back in-place: assembly buffer for z1/z2/q + qproj B operand
#pragma unroll
    for (int g4 = 0; g4 < 4; ++g4) {
        int px = (wv * 4 + g4) * 16 + n15;
        unsigned* bp = (unsigned*)(bstg + px * 40 + 4 * quad);
        bp[0] = (unsigned)f2b(c1[g4][0][0]) | ((unsigned)f2b(c1[g4][0][1]) << 16);
        bp[1] = (unsigned)f2b(c1[g4][0][2]) | ((unsigned)f2b(c1[g4][0][3]) << 16);
        unsigned* bp2 = (unsigned*)(bstg + px * 40 + 16 + 4 * quad);
        bp2[0] = (unsigned)f2b(c1[g4][1][0]) | ((unsigned)f2b(c1[g4][1][1]) << 16);
        bp2[1] = (unsigned)f2b(c1[g4][1][2]) | ((unsigned)f2b(c1[g4][1][3]) << 16);
    }
    __syncthreads();

    if (level == 0) {
        // z0 plane-major fp32 straight from frags (no extra rounding)
        float* z0b = z0out + (size_t)b * C * HW;
#pragma unroll
        for (int g4 = 0; g4 < 4; ++g4) {
            float* rp = z0b + (size_t)(oy + wv * 4 + g4) * W + ox + n15;
#pragma unroll
            for (int r = 0; r < 4; ++r) {
                rp[(size_t)(4 * quad + r) * HW]      = c1[g4][0][r];
                rp[(size_t)(16 + 4 * quad + r) * HW] = c1[g4][1][r];
            }
        }
        // channel means: sum 4 rows locally, 4-stage xor over the 16 px lanes
        float ms[8];
#pragma unroll
        for (int r = 0; r < 4; ++r) {
            ms[r]     = (c1[0][0][r] + c1[1][0][r]) + (c1[2][0][r] + c1[3][0][r]);
            ms[4 + r] = (c1[0][1][r] + c1[1][1][r]) + (c1[2][1][r] + c1[3][1][r]);
        }
#pragma unroll
        for (int r = 0; r < 8; ++r) {
            ms[r] += __shfl_xor(ms[r], 1, 64);
            ms[r] += __shfl_xor(ms[r], 2, 64);
            ms[r] += __shfl_xor(ms[r], 4, 64);
            ms[r] += __shfl_xor(ms[r], 8, 64);
        }
        if (n15 == 0) {
#pragma unroll
            for (int r = 0; r < 4; ++r) {
                zsum[wv][4 * quad + r]      = ms[r];
                zsum[wv][16 + 4 * quad + r] = ms[4 + r];
            }
        }
        // qproj MFMA (B = silu'd z0post in bstg)
        const ushort_t* qwl = pwr + 3 * 1024;
        bf16x8 aq0 = *(const bf16x8*)(qwl + n15 * 32 + quad * 8);
        bf16x8 aq1 = *(const bf16x8*)(qwl + (16 + n15) * 32 + quad * 8);
        f32x4 c2[4][2];
#pragma unroll
        for (int g4 = 0; g4 < 4; ++g4) {
            bf16x8 bf = *(const bf16x8*)(bstg + ((wv * 4 + g4) * 16 + n15) * 40 + quad * 8);
            f32x4 z = {0.0f, 0.0f, 0.0f, 0.0f};
            c2[g4][0] = __builtin_amdgcn_mfma_f32_16x16x32_bf16(aq0, bf, z, 0, 0, 0);
            c2[g4][1] = __builtin_amdgcn_mfma_f32_16x16x32_bf16(aq1, bf, z, 0, 0, 0);
        }
        __syncthreads();   // all qproj B reads done; overwrite with q values
#pragma unroll
        for (int g4 = 0; g4 < 4; ++g4) {
            int px = (wv * 4 + g4) * 16 + n15;
            unsigned* bp = (unsigned*)(bstg + px * 40 + 4 * quad);
            bp[0] = (unsigned)f2b(c2[g4][0][0]) | ((unsigned)f2b(c2[g4][0][1]) << 16);
            bp[1] = (unsigned)f2b(c2[g4][0][2]) | ((unsigned)f2b(c2[g4][0][3]) << 16);
            unsigned* bp2 = (unsigned*)(bstg + px * 40 + 16 + 4 * quad);
            bp2[0] = (unsigned)f2b(c2[g4][1][0]) | ((unsigned)f2b(c2[g4][1][1]) << 16);
            bp2[1] = (unsigned)f2b(c2[g4][1][2]) | ((unsigned)f2b(c2[g4][1][3]) << 16);
        }
        __syncthreads();
        // qpad assembly: thread tid owns px tid -> 4 uint4 stores
        const uint4* rb = (const uint4*)(bstg + (size_t)tid * 40);
        uint4 q0 = rb[0], q1 = rb[1], q2 = rb[2], q3 = rb[3];
        uint4* qd = (uint4*)(qout + (((size_t)b * WP + oy + ty + 1) * WP + ox + tx + 1) * 32);
        qd[0] = q0; qd[1] = q1; qd[2] = q2; qd[3] = q3;
        if (tid < 32)
            atomicAdd(&dall[b * 96 + tid],
                      (zsum[0][tid] + zsum[1][tid] + zsum[2][tid] + zsum[3][tid]) * (1.0f / HW));
    } else {
        // z1/z2 channel-last assembly from bstg
        ushort_t* outcl = (level == 1) ? z1cl : z2cl;
        const uint4* rb = (const uint4*)(bstg + (size_t)tid * 40);
        uint4 q0 = rb[0], q1 = rb[1], q2 = rb[2], q3 = rb[3];
        int p = (oy + ty) * Ws + ox + tx;
        uint4* dst = (uint4*)(outcl + ((size_t)b * HWs + p) * C);
        dst[0] = q0; dst[1] = q1; dst[2] = q2; dst[3] = q3;
    }
}

// ---- offsets/weights, LOCAL to the staged LDS window (PSTR-strided) -------
template<int HC, int WC, int WW>
static __device__ __forceinline__ void calc_off_local(const float* o12, int px, int py,
                                                      int wx0, int wy0,
                                                      int* zoff, float* wgt) {
    float mx = fmaxf(fmaxf(o12[8], o12[9]), fmaxf(o12[10], o12[11]));
    float e0 = __expf(o12[8] - mx), e1 = __expf(o12[9] - mx);
    float e2 = __expf(o12[10] - mx), e3 = __expf(o12[11] - mx);
    float inv = fast_rcp(e0 + e1 + e2 + e3);
    float wk4[4] = {e0 * inv, e1 * inv, e2 * inv, e3 * inv};
    float xc = (px + 0.5f) * ((float)WC / (float)W) - 0.5f;
    float yc = (py + 0.5f) * ((float)HC / (float)H) - 0.5f;
#pragma unroll
    for (int k = 0; k < 4; ++k) {
        float ix = fminf(fmaxf(xc + 2.0f * tanh_f(o12[2 * k]),     0.0f), (float)(WC - 1));
        float iy = fminf(fmaxf(yc + 2.0f * tanh_f(o12[2 * k + 1]), 0.0f), (float)(HC - 1));
        float x0f = floorf(ix), y0f = floorf(iy);
        int x0 = (int)x0f, y0 = (int)y0f;
        int x1 = min(x0 + 1, WC - 1), y1 = min(y0 + 1, HC - 1);
        float wx = ix - x0f, wy = iy - y0f;
        float wk = wk4[k];
        int lx0 = x0 - wx0, ly0 = y0 - wy0;
        int lx1 = x1 - wx0, ly1 = y1 - wy0;
        zoff[4 * k + 0] = (ly0 * WW + lx0) * PSTR; wgt[4 * k + 0] = (1.0f - wx) * (1.0f - wy) * wk;
        zoff[4 * k + 1] = (ly0 * WW + lx1) * PSTR; wgt[4 * k + 1] = wx * (1.0f - wy) * wk;
        zoff[4 * k + 2] = (ly1 * WW + lx0) * PSTR; wgt[4 * k + 2] = (1.0f - wx) * wy * wk;
        zoff[4 * k + 3] = (ly1 * WW + lx1) * PSTR; wgt[4 * k + 3] = wx * wy * wk;
    }
}

// ---- deform tail: stage coarse window in LDS, gather via ds_read_b128 -----
// Window bound proof: ix = clamp(xc + 2*tanh, 0, WC-1), xc in
// [(ox+0.5)*WC/W - 0.5, (ox+15.5)*WC/W - 0.5] -> x0 in [ox>>SH - 3,
// ox>>SH + 9], x1 <= ox>>SH + 10 (SH=1) / +6 (SH=2) -> WW = 14 / 10.
// Points at 80B stride (r14): bank stride 20 -> alias only at point
// distance 8 (was 2 at 64B). r16's extra swizzle REGRESSED - keep plain.
// LDS: ysum [0,512), zwin [512, 512 + WW*WW*80) <= 16192 < 20736.
// r17: gather in two batches of 8 (bit-identical), halving vv[] liveness.
// r18: accumulators as v2f -> v_pk_fma_f32; per-channel order unchanged
// (channel c still sums j=0..15 sequentially) -> bit-identical.
template<int HC, int WC, int WW, int SH>
static __device__ __forceinline__ void deform_tail(
        const float* o12, int ox, int oy, int px, int py,
        const ushort_t* __restrict__ zb, char* smem,
        float* __restrict__ d, float* __restrict__ dslot,
        int tid, int lane, int wv) {
    float (*ysum)[32] = (float (*)[32])smem;            // [0, 512)
    ushort_t* zwin = (ushort_t*)(smem + 512);           // [512, ...)
    int wx0 = min(max((ox >> SH) - 3, 0), WC - WW);
    int wy0 = min(max((oy >> SH) - 3, 0), HC - WW);

    // local offsets + weights (register work, overlaps staging issue)
    int off[16]; float wg[16];
    calc_off_local<HC, WC, WW>(o12, px, py, wx0, wy0, off, wg);

    // stage the window: WW*WW points x 64 B data in 80 B frames, coalesced
    {
        uint4* zw = (uint4*)(smem + 512);
        const ushort_t* zo = zb + ((size_t)wy0 * WC + wx0) * C;
        for (int i = tid; i < WW * WW * 4; i += 256) {
            int pnt = i >> 2, ch = i & 3;
            int r = pnt / WW, c = pnt - r * WW;
            zw[pnt * 5 + ch] = *(const uint4*)(zo + ((size_t)r * WC + c) * C + ch * 8);
        }
    }
    __syncthreads();

#pragma unroll
    for (int c8 = 0; c8 < 4; ++c8) {
        v2f a0 = {0.0f, 0.0f}, a1 = {0.0f, 0.0f};
        v2f a2 = {0.0f, 0.0f}, a3 = {0.0f, 0.0f};
#pragma unroll
        for (int h = 0; h < 2; ++h) {
            uint4 vv[8];
#pragma unroll
            for (int j = 0; j < 8; ++j)
                vv[j] = *(const uint4*)(zwin + off[8 * h + j] + c8 * 8);
#pragma unroll
            for (int j = 0; j < 8; ++j) {
                float wj = wg[8 * h + j];
                v2f w2 = {wj, wj};
                a0 += w2 * (v2f){bl(vv[j].x), bh(vv[j].x)};
                a1 += w2 * (v2f){bl(vv[j].y), bh(vv[j].y)};
                a2 += w2 * (v2f){bl(vv[j].z), bh(vv[j].z)};
                a3 += w2 * (v2f){bl(vv[j].w), bh(vv[j].w)};
            }
        }
        d[(size_t)(c8 * 8 + 0) * HW] = a0.x;
        d[(size_t)(c8 * 8 + 1) * HW] = a0.y;
        d[(size_t)(c8 * 8 + 2) * HW] = a1.x;
        d[(size_t)(c8 * 8 + 3) * HW] = a1.y;
        d[(size_t)(c8 * 8 + 4) * HW] = a2.x;
        d[(size_t)(c8 * 8 + 5) * HW] = a2.y;
        d[(size_t)(c8 * 8 + 6) * HW] = a3.x;
        d[(size_t)(c8 * 8 + 7) * HW] = a3.y;
        // channel means: butterfly-split reduce (10 shuffles for 8 channels)
        float s = red8_ch(a0.x, a0.y, a1.x, a1.y, a2.x, a2.y, a3.x, a3.y, lane);
        if (lane < 8)
            ysum[wv][c8 * 8 + ((lane & 1) * 4 + (lane & 2) + ((lane >> 2) & 1))] = s;
    }
    __syncthreads();
    if (tid < 32) {
        float s = ysum[0][tid] + ysum[1][tid] + ysum[2][tid] + ysum[3][tid];
        atomicAdd(dslot + tid, s * (1.0f / HW));
    }
}

// ---- one head per block (blockIdx.z): MFMA 3x3 conv + LDS-window deform ---
// (256,5) = cap 51; r17 measured VGPR 48, no spill.
__global__ __launch_bounds__(256, 5) void head_deform_kernel(
        const ushort_t* __restrict__ qpad,
        const ushort_t* __restrict__ z1, const ushort_t* __restrict__ z2,
        const ushort_t* __restrict__ w1ra, const ushort_t* __restrict__ w1rb,
        const float* __restrict__ w2a, const float* __restrict__ b2a,
        const float* __restrict__ w2b, const float* __restrict__ b2b,
        float* __restrict__ y1, float* __restrict__ y2, float* __restrict__ dall) {
    __shared__ __align__(16) char smem[TAREA * C * 2];      // 20736 B
    ushort_t* tile = (ushort_t*)smem;
    unsigned* hidw = (unsigned*)smem;                       // bytes [0, 9216)
    int tid = threadIdx.x, b = blockIdx.y, hsel = blockIdx.z;
    int ox = (blockIdx.x & 15) * TILE, oy = (blockIdx.x >> 4) * TILE;
    int lane = tid & 63, wv = tid >> 6;
    int n15 = lane & 15, quad = lane >> 4;
    int tx = tid & 15, ty = tid >> 4;

    // stage q tile (rows contiguous in padded channel-last q)
    {
        const ushort_t* base = qpad + ((size_t)b * WP + oy) * WP * 32;
        uint4* tl = (uint4*)tile;
        for (int i = tid; i < 1296; i += 256) {      // 18 rows * 72 16B-chunks
            int yy = i / 72, r = i - yy * 72;
            tl[i] = *(const uint4*)(base + ((size_t)yy * WP + ox) * 32 + r * 8);
        }
    }
    __syncthreads();

    const ushort_t* w1r = hsel ? w1rb : w1ra;
    bf16x8 af[9];
#pragma unroll
    for (int j = 0; j < 9; ++j)
        af[j] = *(const bf16x8*)(w1r + n15 * 288 + j * 32 + quad * 8);
    unsigned pk[8];
#pragma unroll
    for (int g = 0; g < 4; ++g) {
        int yrow = wv * 4 + g;
        f32x4 acc = {0.0f, 0.0f, 0.0f, 0.0f};
#pragma unroll
        for (int jy = 0; jy < 3; ++jy)
#pragma unroll
            for (int jx = 0; jx < 3; ++jx) {
                const bf16x8* bp = (const bf16x8*)(tile +
                    ((yrow + jy) * HALO + n15 + jx) * 32 + quad * 8);
                acc = __builtin_amdgcn_mfma_f32_16x16x32_bf16(
                    af[jy * 3 + jx], *bp, acc, 0, 0, 0);
            }
        pk[2 * g]     = (unsigned)f2b(acc[0]) | ((unsigned)f2b(acc[1]) << 16);
        pk[2 * g + 1] = (unsigned)f2b(acc[2]) | ((unsigned)f2b(acc[3]) << 16);
    }
    __syncthreads();   // ALL waves done reading tile before hidw overwrites it
#pragma unroll
    for (int g = 0; g < 4; ++g) {
        int pxl = (wv * 4 + g) * 16 + n15;
        hidw[pxl * 9 + quad * 2]     = pk[2 * g];
        hidw[pxl * 9 + quad * 2 + 1] = pk[2 * g + 1];
    }
    // hidw write->read is same-wave (pxl in [wv*64, wv*64+64)); lgkmcnt covers it
    float hid[CH];
#pragma unroll
    for (int j = 0; j < 8; ++j) {
        unsigned u = hidw[tid * 9 + j];
        hid[2 * j]     = silu_f(bl(u));
        hid[2 * j + 1] = silu_f(bh(u));
    }

    // ---- tail for this head ----
    const float* w2 = hsel ? w2b : w2a;
    const float* bs = hsel ? b2b : b2a;
    float o12[CO];
#pragma unroll
    for (int j = 0; j < CO; ++j) {
        float a = bs[j];
#pragma unroll
        for (int i = 0; i < CH; ++i) a += w2[j * CH + i] * hid[i];
        o12[j] = a;
    }
    __syncthreads();   // all waves done reading hidw; zwin may overwrite it

    int px = ox + tx, py = oy + ty;
    int p = py * W + px;
    if (hsel == 0)
        deform_tail<H1, W1, 14, 1>(o12, ox, oy, px, py,
            z1 + (size_t)b * HW1 * C, smem,
            y1 + (size_t)b * C * HW + p, dall + b * 96 + 32, tid, lane, wv);
    else
        deform_tail<H2, W2, 10, 2>(o12, ox, oy, px, py,
            z2 + (size_t)b * HW2 * C, smem,
            y2 + (size_t)b * C * HW + p, dall + b * 96 + 64, tid, lane, wv);
}

// ---- fused gate (alpha recompute per block) + mix + 1x1 conv + residual ---
__global__ __launch_bounds__(256, 4) void final_kernel(
        const float* __restrict__ x,
        const float* __restrict__ z0, const float* __restrict__ y1,
        const float* __restrict__ y2, const float* __restrict__ dall,
        const float* __restrict__ rw1, const float* __restrict__ rb1,
        const float* __restrict__ rw2, const float* __restrict__ rb2,
        const float* __restrict__ fw, float* __restrict__ out) {
    __shared__ float ws[C * C];
    __shared__ float hid[32];
    __shared__ float a3[3];
    int tid = threadIdx.x;
    int idx = blockIdx.x * blockDim.x + tid;
    int b = idx / HW, p = idx - b * HW;
    for (int i = tid; i < C * C; i += blockDim.x) ws[i] = fw[i];
    if (tid < 32) {
        float a = rb1[tid];
        for (int k = 0; k < 96; ++k) a += dall[b * 96 + k] * rw1[k * 32 + tid];
        hid[tid] = silu_f(a);
    }
    __syncthreads();
    if (tid == 0) {
        float lg[3];
#pragma unroll
        for (int t = 0; t < 3; ++t) {
            float acc = rb2[t];
            for (int jj = 0; jj < 32; ++jj) acc += hid[jj] * rw2[jj * 3 + t];
            lg[t] = acc;
        }
        float mx = fmaxf(lg[0], fmaxf(lg[1], lg[2]));
        float e0 = __expf(lg[0] - mx), e1 = __expf(lg[1] - mx), e2 = __expf(lg[2] - mx);
        float inv = fast_rcp(e0 + e1 + e2);
        a3[0] = e0 * inv; a3[1] = e1 * inv; a3[2] = e2 * inv;
    }
    __syncthreads();
    float a0 = a3[0], a1 = a3[1], a2 = a3[2];
    size_t base = (size_t)b * C * HW + p;
    float mix[C];
#pragma unroll
    for (int i = 0; i < C; ++i) {
        size_t e = base + (size_t)i * HW;
        mix[i] = a0 * z0[e] + a1 * y1[e] + a2 * y2[e];
    }
#pragma unroll 4
    for (int o = 0; o < C; ++o) {
        float acc = 0.0f;
#pragma unroll
        for (int i = 0; i < C; ++i) acc += ws[o * C + i] * mix[i];
        size_t e = base + (size_t)o * HW;
        out[e] = acc + x[e];
    }
}

// ---------------------------------------------------------------------------
extern "C" void kernel_launch(void* const* d_in, const int* in_sizes, int n_in,
                              void* d_out, int out_size, void* d_ws, size_t ws_size,
                              hipStream_t stream) {
    const float* x       = (const float*)d_in[0];
    const float* ds_dw[3] = {(const float*)d_in[1],  (const float*)d_in[7],  (const float*)d_in[13]};
    const float* ds_pw[3] = {(const float*)d_in[2],  (const float*)d_in[8],  (const float*)d_in[14]};
    const float* ds_g[3]  = {(const float*)d_in[3],  (const float*)d_in[9],  (const float*)d_in[15]};
    const float* ds_b[3]  = {(const float*)d_in[4],  (const float*)d_in[10], (const float*)d_in[16]};
    const float* ds_m[3]  = {(const float*)d_in[5],  (const float*)d_in[11], (const float*)d_in[17]};
    const float* ds_v[3]  = {(const float*)d_in[6],  (const float*)d_in[12], (const float*)d_in[18]};
    const float* qproj_w = (const float*)d_in[19];
    const float* h1_w1   = (const float*)d_in[20];
    const float* h1_w2   = (const float*)d_in[21];
    const float* h1_b2   = (const float*)d_in[22];
    const float* h2_w1   = (const float*)d_in[23];
    const float* h2_w2   = (const float*)d_in[24];
    const float* h2_b2   = (const float*)d_in[25];
    const float* r_w1    = (const float*)d_in[26];
    const float* r_b1    = (const float*)d_in[27];
    const float* r_w2    = (const float*)d_in[28];
    const float* r_b2    = (const float*)d_in[29];
    const float* final_w = (const float*)d_in[30];
    float* out = (float*)d_out;

    constexpr size_t N0 = (size_t)B * C * HW;
    constexpr size_t N1 = (size_t)B * C * HW1;
    constexpr size_t N2 = (size_t)B * C * HW2;
    constexpr size_t NQ = ((size_t)B * WP * WP * 32 + 1) / 2;   // qpad (u16) in floats

    float* w = (float*)d_ws;
    float* z0   = w; w += N0;      // plane fp32
    float* y1   = w; w += N0;      // plane fp32
    float* y2   = w; w += N0;      // plane fp32
    ushort_t* z1cl = (ushort_t*)w; w += N1 / 2;   // bf16 channel-last
    ushort_t* z2cl = (ushort_t*)w; w += N2 / 2;   // bf16 channel-last
    float* s1   = w; w += N1;
    ushort_t* qpad = (ushort_t*)w; w += NQ;
    ushort_t* w1ra = (ushort_t*)w; w += 2304;   // 4608 bf16
    ushort_t* w1rb = (ushort_t*)w; w += 2304;
    ushort_t* pwr  = (ushort_t*)w; w += 2048;   // 4096 bf16: pw0,pw1,pw2,qw
    float* dall  = w; w += 512;
    (void)ws_size; (void)in_sizes; (void)n_in; (void)out_size;

    const int T = 256;
    auto g = [](size_t n, int t) { return (int)((n + t - 1) / t); };

    pre_kernel<<<g(N1 + 4112 + 512 + 4608 + 4608 + 4096, T), T, 0, stream>>>(
        x, s1, qpad, dall, h1_w1, h2_w1, w1ra, w1rb,
        ds_pw[0], ds_pw[1], ds_pw[2], qproj_w, pwr);

    DsParams p0 = {ds_dw[0], ds_g[0], ds_b[0], ds_m[0], ds_v[0]};
    DsParams p1 = {ds_dw[1], ds_g[1], ds_b[1], ds_m[1], ds_v[1]};
    DsParams p2 = {ds_dw[2], ds_g[2], ds_b[2], ds_m[2], ds_v[2]};
    fused_ds_all_kernel<<<1344, T, 0, stream>>>(
        x, s1, p0, p1, p2, pwr, z0, z1cl, z2cl, qpad, dall);

    head_deform_kernel<<<dim3((H / TILE) * (W / TILE), B, 2), T, 0, stream>>>(
        qpad, z1cl, z2cl, w1ra, w1rb, h1_w2, h1_b2, h2_w2, h2_b2, y1, y2, dall);

    final_kernel<<<g((size_t)B * HW, T), T, 0, stream>>>(
        x, z0, y1, y2, dall, r_w1, r_b1, r_w2, r_b2, final_w, out);
}

// Round 13
// 264.094 us; speedup vs baseline: 1.0294x; 1.0294x over previous
//
#include <hip/hip_runtime.h>
#include <math.h>

// ---------------------------------------------------------------------------
// CSDM pipeline on MI355X. fp32 in/out, fp32/bf16 intermediates in d_ws.
// B=4, C=32, H=W=256. MFMA head conv; bf16 channel-last gather sources;
// channel means fused into producer kernels (no mean pass).
// Layout law (r6): bulk WRITES plane-major dense; gather READS channel-last.
// r7: head kernel split per-head across blockIdx.z (2048 blocks), LDS union.
// r8/r11 EMPIRICAL LAW: hipcc VGPR cap for __launch_bounds__(256,N) ~256/N
// ((256,3)->84, (256,4)->64, (256,5)->51, (256,6)->40, (256,7)->36).
// Raising N is safe ONLY when natural VGPR <= cap; else scratch spill
// (matched FETCH+WRITE jump). ds_all natural 36 -> N=6 OK (r15).
// r9: all three ds levels in ONE launch. r10: pw+qproj MFMA-ized.
// r12: cross-run variance on latency-bound kernels is +/-15-30%; only
// same-run comparisons are interpretable. ~125us of dur_us is constant
// harness overhead; kernel-time budget is ~140us.
// r13: deform gathers LDS-staged (tanh-bounded 14x14/10x10 windows).
// r14: window points 80B stride; gate fused into final.
// r15: ds_all (256,6) + s1 restored. 264.7 = champion.
// r16 FAILED+REVERTED: slot-XOR swizzle + pk-fma + addressing at VGPR cap.
// r17: gather 2x8 split + (256,5): VGPR 48, no spill, 265.7 (~= champion).
// r18 FAILED+REVERTED: pk-fma isolated still spills (v2f accumulators force
// aligned pairs; WRITE 75->89MB). pk-math on this kernel: CLOSED.
// r19: revert to r17 verbatim. Head at structural floor (~51us); ds_all,
// final, pre each within ~10-15% of their floors; rest is harness overhead.
// ---------------------------------------------------------------------------

constexpr int B = 4, C = 32, H = 256, W = 256;
constexpr int HW = H * W;
constexpr int H1 = 128, W1 = 128, HW1 = H1 * W1;
constexpr int H2 = 64,  W2 = 64,  HW2 = H2 * W2;
constexpr int CH = 16;   // head hidden channels
constexpr int CO = 12;   // head output channels
constexpr int TILE = 16;
constexpr int HALO = 18;
constexpr int TAREA = HALO * HALO;   // 324
constexpr int WP = 258;              // padded q edge
constexpr int PSTR = 40;             // zwin point stride in halfwords (80 B)

typedef unsigned short ushort_t;
typedef __attribute__((ext_vector_type(8))) short bf16x8;
typedef __attribute__((ext_vector_type(4))) float f32x4;
typedef __attribute__((ext_vector_type(2))) float v2f;

static __device__ __forceinline__ float fast_rcp(float x) { return __builtin_amdgcn_rcpf(x); }
static __device__ __forceinline__ float silu_f(float x) { return x * fast_rcp(1.0f + __expf(-x)); }
static __device__ __forceinline__ float tanh_f(float x) {
    float xc = fminf(fmaxf(x, -15.0f), 15.0f);
    float e = __expf(2.0f * xc);
    return (e - 1.0f) * fast_rcp(e + 1.0f);
}
static __device__ __forceinline__ ushort_t f2b(float f) {   // fp32 -> bf16 RNE
    unsigned u = __float_as_uint(f);
    return (ushort_t)((u + 0x7fffu + ((u >> 16) & 1u)) >> 16);
}
static __device__ __forceinline__ float bl(unsigned u) { return __uint_as_float(u << 16); }
static __device__ __forceinline__ float bh(unsigned u) { return __uint_as_float(u & 0xffff0000u); }

// Multi-value butterfly: 8 per-thread channel values -> full-wave sum of
// channel c(lane)=4*b0+2*b1+b2 in lane. 10 shuffles vs 48 for 8 wave_sums.
static __device__ __forceinline__ float red8_ch(float v0, float v1, float v2, float v3,
                                                float v4, float v5, float v6, float v7,
                                                int lane) {
    bool q0 = (lane & 1) != 0, q1 = (lane & 2) != 0, q2 = (lane & 4) != 0;
    float a0 = (q0 ? v4 : v0) + __shfl_xor(q0 ? v0 : v4, 1, 64);
    float a1 = (q0 ? v5 : v1) + __shfl_xor(q0 ? v1 : v5, 1, 64);
    float a2 = (q0 ? v6 : v2) + __shfl_xor(q0 ? v2 : v6, 1, 64);
    float a3 = (q0 ? v7 : v3) + __shfl_xor(q0 ? v3 : v7, 1, 64);
    float c0 = (q1 ? a2 : a0) + __shfl_xor(q1 ? a0 : a2, 2, 64);
    float c1 = (q1 ? a3 : a1) + __shfl_xor(q1 ? a1 : a3, 2, 64);
    float e  = (q2 ? c1 : c0) + __shfl_xor(q2 ? c0 : c1, 4, 64);
    e += __shfl_xor(e, 8, 64);
    e += __shfl_xor(e, 16, 64);
    e += __shfl_xor(e, 32, 64);
    return e;
}

// ---- pre: pool2 (x->s1) + qpad border + dall zero + weight reorders -------
__global__ void pre_kernel(const float* __restrict__ x, float* __restrict__ s1,
                           ushort_t* __restrict__ qpad, float* __restrict__ dall,
                           const float* __restrict__ h1w1, const float* __restrict__ h2w1,
                           ushort_t* __restrict__ w1ra, ushort_t* __restrict__ w1rb,
                           const float* __restrict__ pw0, const float* __restrict__ pw1,
                           const float* __restrict__ pw2, const float* __restrict__ qw,
                           ushort_t* __restrict__ pwr) {
    int idx = blockIdx.x * blockDim.x + threadIdx.x;
    constexpr int NP = B * C * HW1;
    if (idx < NP) {
        int wo = idx % W1; int t = idx / W1;
        int ho = t % H1;   t /= H1;
        const float* src = x + ((size_t)t * H + (size_t)ho * 2) * W + (size_t)wo * 2;
        s1[idx] = (src[0] + src[1] + src[W] + src[W + 1]) * 0.25f;
        return;
    }
    int i = idx - NP;
    if (i < 4112) {                       // qpad border (4*1028)
        int b = i / 1028, r = i % 1028;
        int y, xx;
        if (r < 258)      { y = 0;           xx = r; }
        else if (r < 516) { y = 257;         xx = r - 258; }
        else if (r < 772) { y = r - 516 + 1; xx = 0; }
        else              { y = r - 772 + 1; xx = 257; }
        uint4 z4 = {0, 0, 0, 0};
        uint4* p = (uint4*)(qpad + (((size_t)b * WP + y) * WP + xx) * 32);
        p[0] = z4; p[1] = z4; p[2] = z4; p[3] = z4;
        return;
    }
    i -= 4112;
    if (i < 512) { dall[i] = 0.0f; return; }
    i -= 512;
    if (i < 4608) {                       // w1ra[o*288 + tap*32 + ci]
        int o = i / 288, k = i - o * 288;
        int j = k >> 5, ci = k & 31;
        w1ra[i] = f2b(h1w1[(o * C + ci) * 9 + j]);
        return;
    }
    i -= 4608;
    if (i < 4608) {
        int o = i / 288, k = i - o * 288;
        int j = k >> 5, ci = k & 31;
        w1rb[i] = f2b(h2w1[(o * C + ci) * 9 + j]);
        return;
    }
    i -= 4608;
    if (i < 4096) {                       // pwr[m][och][inch] bf16 row-major
        int mm = i >> 10, k = i & 1023;
        int o = k >> 5, ci = k & 31;
        const float* wsrc = (mm == 0) ? pw0 : (mm == 1) ? pw1 : (mm == 2) ? pw2 : qw;
        pwr[i] = f2b(wsrc[o * C + ci]);
    }
}

// ---- fused ds_block, all 3 levels in one launch, MFMA pointwise -----------
// blockIdx.x: [0,1024) level0 (z0+qproj+means, reads x), [1024,1280) level1
// (z1cl, reads s1), [1280,1344) level2 (z2cl, pools 2x2 from s1).
struct DsParams {
    const float* dw;
    const float* g;  const float* b;  const float* m; const float* v;
};

// launch_bounds (256,6): natural VGPR=36 <= cap(6)=40 -> no spill; LDS
// 6x23040=138KB -> 6 blocks/CU; grid 1344 <= 1536 fully resident.
__global__ __launch_bounds__(256, 6) void fused_ds_all_kernel(
        const float* __restrict__ x, const float* __restrict__ s1,
        DsParams P0, DsParams P1, DsParams P2, const ushort_t* __restrict__ pwr,
        float* __restrict__ z0out, ushort_t* __restrict__ z1cl,
        ushort_t* __restrict__ z2cl, ushort_t* __restrict__ qout,
        float* __restrict__ dall) {
    // tileu (20736 B) and bstg (256 px * 40 ch bf16 = 20480 B) share space.
    __shared__ __align__(16) char smem[16 * TAREA * 4];
    unsigned* tileu = (unsigned*)smem;
    ushort_t* bstg  = (ushort_t*)smem;
    __shared__ v2f dwp[16 * 9];
    __shared__ __align__(16) float sc[32], sh[32];
    __shared__ float zsum[4][32];

    int bx = blockIdx.x;
    int level = (bx < 1024) ? 0 : (bx < 1280 ? 1 : 2);
    int rel = bx - ((level == 0) ? 0 : (level == 1 ? 1024 : 1280));
    int Hs = (level == 0) ? H : (level == 1 ? H1 : H2);
    int Ws = Hs;
    int tilesX = Ws / TILE;
    int tilesT = tilesX * (Hs / TILE);
    int b = rel / tilesT;
    int tile = rel - b * tilesT;
    int ox = (tile % tilesX) * TILE;
    int oy = (tile / tilesX) * TILE;
    DsParams P = (level == 0) ? P0 : (level == 1 ? P1 : P2);
    int HWs = Hs * Ws;
    int tid = threadIdx.x;
    int lane = tid & 63, wv = tid >> 6;
    int n15 = lane & 15, quad = lane >> 4;
    int tx = tid & 15, ty = tid >> 4;

    for (int i = tid; i < 16 * 9; i += 256) {
        int c2 = i / 9, j = i - c2 * 9;
        dwp[i] = (v2f){P.dw[(2 * c2) * 9 + j], P.dw[(2 * c2 + 1) * 9 + j]};
    }
    if (tid < 32) {
        float s0 = P.g[tid] * rsqrtf(P.v[tid] + 1e-5f);
        sc[tid] = s0;
        sh[tid] = P.b[tid] - P.m[tid] * s0;
    }
    const float* xb = x + (size_t)b * C * HW;
    const float* s1b = s1 + (size_t)b * C * HW1;
    for (int i = tid; i < 16 * TAREA; i += 256) {
        int c2 = i / TAREA, r = i - c2 * TAREA;
        int yy = r / HALO, xx = r - yy * HALO;
        int gy = oy - 1 + yy, gx = ox - 1 + xx;
        float v0 = 0.0f, v1 = 0.0f;
        if (gy >= 0 && gy < Hs && gx >= 0 && gx < Ws) {
            if (level == 0) {
                const float* sp = xb + (size_t)(2 * c2) * HW + (size_t)gy * W + gx;
                v0 = sp[0]; v1 = sp[HW];
            } else if (level == 1) {
                const float* sp = s1b + (size_t)(2 * c2) * HW1 + (size_t)gy * W1 + gx;
                v0 = sp[0]; v1 = sp[HW1];
            } else {
                // s2 = 2x2 mean of s1 (old pool4_kernel numerics)
                const float* sp = s1b + (size_t)(2 * c2) * HW1 + (size_t)(gy * 2) * W1 + gx * 2;
                v0 = (sp[0] + sp[1] + sp[W1] + sp[W1 + 1]) * 0.25f;
                sp += HW1;
                v1 = (sp[0] + sp[1] + sp[W1] + sp[W1 + 1]) * 0.25f;
            }
        }
        tileu[i] = (unsigned)f2b(v0) | ((unsigned)f2b(v1) << 16);
    }
    __syncthreads();

    // ---- depthwise conv (VALU; per-channel, not matmul-shaped) ----
    int off[9];
#pragma unroll
    for (int jy = 0; jy < 3; ++jy)
#pragma unroll
        for (int jx = 0; jx < 3; ++jx)
            off[jy * 3 + jx] = (ty + jy) * HALO + tx + jx;

    v2f t2[16];
#pragma unroll
    for (int c2 = 0; c2 < 16; ++c2) {
        v2f s = {0.0f, 0.0f};
        const unsigned* tp = tileu + c2 * TAREA;
#pragma unroll
        for (int j = 0; j < 9; ++j) {
            unsigned u = tp[off[j]];
            v2f val = {bl(u), bh(u)};
            s += dwp[c2 * 9 + j] * val;
        }
        t2[c2] = s;
    }
    __syncthreads();   // all dwconv tileu reads done; bstg may overwrite

    // ---- stage dwconv out as bf16 [px][40ch] (pad 40 -> 2-way banks) ----
    {
        unsigned up[16];
#pragma unroll
        for (int j = 0; j < 16; ++j)
            up[j] = (unsigned)f2b(t2[j].x) | ((unsigned)f2b(t2[j].y) << 16);
        uint4* bw = (uint4*)(bstg + (size_t)tid * 40);
#pragma unroll
        for (int j = 0; j < 4; ++j)
            bw[j] = make_uint4(up[4 * j], up[4 * j + 1], up[4 * j + 2], up[4 * j + 3]);
    }
    __syncthreads();

    // ---- MFMA pointwise: A = weights [och 16][inch 32], B = [inch 32][px 16]
    const ushort_t* pwl = pwr + level * 1024;
    bf16x8 apw0 = *(const bf16x8*)(pwl + n15 * 32 + quad * 8);
    bf16x8 apw1 = *(const bf16x8*)(pwl + (16 + n15) * 32 + quad * 8);
    f32x4 c1[4][2];
#pragma unroll
    for (int g4 = 0; g4 < 4; ++g4) {
        bf16x8 bf = *(const bf16x8*)(bstg + ((wv * 4 + g4) * 16 + n15) * 40 + quad * 8);
        f32x4 z = {0.0f, 0.0f, 0.0f, 0.0f};
        c1[g4][0] = __builtin_amdgcn_mfma_f32_16x16x32_bf16(apw0, bf, z, 0, 0, 0);
        c1[g4][1] = __builtin_amdgcn_mfma_f32_16x16x32_bf16(apw1, bf, z, 0, 0, 0);
    }
    // BN + SiLU on C-frags: och = 16*t + 4*quad + r, px = n15 of row wv*4+g4
    f32x4 sc0 = *(const f32x4*)(sc + 4 * quad);
    f32x4 sc1 = *(const f32x4*)(sc + 16 + 4 * quad);
    f32x4 sh0 = *(const f32x4*)(sh + 4 * quad);
    f32x4 sh1 = *(const f32x4*)(sh + 16 + 4 * quad);
#pragma unroll
    for (int g4 = 0; g4 < 4; ++g4)
#pragma unroll
        for (int r = 0; r < 4; ++r) {
            c1[g4][0][r] = silu_f(c1[g4][0][r] * sc0[r] + sh0[r]);
            c1[g4][1][r] = silu_f(c1[g4][1][r] * sc1[r] + sh1[r]);
        }
    __syncthreads();   // all MFMA1 B reads done; overwrite bstg with silu'd

    // silu'd bf16 back in-place: assembly buffer for z1/z2/q + qproj B operand
#pragma unroll
    for (int g4 = 0; g4 < 4; ++g4) {
        int px = (wv * 4 + g4) * 16 + n15;
        unsigned* bp = (unsigned*)(bstg + px * 40 + 4 * quad);
        bp[0] = (unsigned)f2b(c1[g4][0][0]) | ((unsigned)f2b(c1[g4][0][1]) << 16);
        bp[1] = (unsigned)f2b(c1[g4][0][2]) | ((unsigned)f2b(c1[g4][0][3]) << 16);
        unsigned* bp2 = (unsigned*)(bstg + px * 40 + 16 + 4 * quad);
        bp2[0] = (unsigned)f2b(c1[g4][1][0]) | ((unsigned)f2b(c1[g4][1][1]) << 16);
        bp2[1] = (unsigned)f2b(c1[g4][1][2]) | ((unsigned)f2b(c1[g4][1][3]) << 16);
    }
    __syncthreads();

    if (level == 0) {
        // z0 plane-major fp32 straight from frags (no extra rounding)
        float* z0b = z0out + (size_t)b * C * HW;
#pragma unroll
        for (int g4 = 0; g4 < 4; ++g4) {
            float* rp = z0b + (size_t)(oy + wv * 4 + g4) * W + ox + n15;
#pragma unroll
            for (int r = 0; r < 4; ++r) {
                rp[(size_t)(4 * quad + r) * HW]      = c1[g4][0][r];
                rp[(size_t)(16 + 4 * quad + r) * HW] = c1[g4][1][r];
            }
        }
        // channel means: sum 4 rows locally, 4-stage xor over the 16 px lanes
        float ms[8];
#pragma unroll
        for (int r = 0; r < 4; ++r) {
            ms[r]     = (c1[0][0][r] + c1[1][0][r]) + (c1[2][0][r] + c1[3][0][r]);
            ms[4 + r] = (c1[0][1][r] + c1[1][1][r]) + (c1[2][1][r] + c1[3][1][r]);
        }
#pragma unroll
        for (int r = 0; r < 8; ++r) {
            ms[r] += __shfl_xor(ms[r], 1, 64);
            ms[r] += __shfl_xor(ms[r], 2, 64);
            ms[r] += __shfl_xor(ms[r], 4, 64);
            ms[r] += __shfl_xor(ms[r], 8, 64);
        }
        if (n15 == 0) {
#pragma unroll
            for (int r = 0; r < 4; ++r) {
                zsum[wv][4 * quad + r]      = ms[r];
                zsum[wv][16 + 4 * quad + r] = ms[4 + r];
            }
        }
        // qproj MFMA (B = silu'd z0post in bstg)
        const ushort_t* qwl = pwr + 3 * 1024;
        bf16x8 aq0 = *(const bf16x8*)(qwl + n15 * 32 + quad * 8);
        bf16x8 aq1 = *(const bf16x8*)(qwl + (16 + n15) * 32 + quad * 8);
        f32x4 c2[4][2];
#pragma unroll
        for (int g4 = 0; g4 < 4; ++g4) {
            bf16x8 bf = *(const bf16x8*)(bstg + ((wv * 4 + g4) * 16 + n15) * 40 + quad * 8);
            f32x4 z = {0.0f, 0.0f, 0.0f, 0.0f};
            c2[g4][0] = __builtin_amdgcn_mfma_f32_16x16x32_bf16(aq0, bf, z, 0, 0, 0);
            c2[g4][1] = __builtin_amdgcn_mfma_f32_16x16x32_bf16(aq1, bf, z, 0, 0, 0);
        }
        __syncthreads();   // all qproj B reads done; overwrite with q values
#pragma unroll
        for (int g4 = 0; g4 < 4; ++g4) {
            int px = (wv * 4 + g4) * 16 + n15;
            unsigned* bp = (unsigned*)(bstg + px * 40 + 4 * quad);
            bp[0] = (unsigned)f2b(c2[g4][0][0]) | ((unsigned)f2b(c2[g4][0][1]) << 16);
            bp[1] = (unsigned)f2b(c2[g4][0][2]) | ((unsigned)f2b(c2[g4][0][3]) << 16);
            unsigned* bp2 = (unsigned*)(bstg + px * 40 + 16 + 4 * quad);
            bp2[0] = (unsigned)f2b(c2[g4][1][0]) | ((unsigned)f2b(c2[g4][1][1]) << 16);
            bp2[1] = (unsigned)f2b(c2[g4][1][2]) | ((unsigned)f2b(c2[g4][1][3]) << 16);
        }
        __syncthreads();
        // qpad assembly: thread tid owns px tid -> 4 uint4 stores
        const uint4* rb = (const uint4*)(bstg + (size_t)tid * 40);
        uint4 q0 = rb[0], q1 = rb[1], q2 = rb[2], q3 = rb[3];
        uint4* qd = (uint4*)(qout + (((size_t)b * WP + oy + ty + 1) * WP + ox + tx + 1) * 32);
        qd[0] = q0; qd[1] = q1; qd[2] = q2; qd[3] = q3;
        if (tid < 32)
            atomicAdd(&dall[b * 96 + tid],
                      (zsum[0][tid] + zsum[1][tid] + zsum[2][tid] + zsum[3][tid]) * (1.0f / HW));
    } else {
        // z1/z2 channel-last assembly from bstg
        ushort_t* outcl = (level == 1) ? z1cl : z2cl;
        const uint4* rb = (const uint4*)(bstg + (size_t)tid * 40);
        uint4 q0 = rb[0], q1 = rb[1], q2 = rb[2], q3 = rb[3];
        int p = (oy + ty) * Ws + ox + tx;
        uint4* dst = (uint4*)(outcl + ((size_t)b * HWs + p) * C);
        dst[0] = q0; dst[1] = q1; dst[2] = q2; dst[3] = q3;
    }
}

// ---- offsets/weights, LOCAL to the staged LDS window (PSTR-strided) -------
template<int HC, int WC, int WW>
static __device__ __forceinline__ void calc_off_local(const float* o12, int px, int py,
                                                      int wx0, int wy0,
                                                      int* zoff, float* wgt) {
    float mx = fmaxf(fmaxf(o12[8], o12[9]), fmaxf(o12[10], o12[11]));
    float e0 = __expf(o12[8] - mx), e1 = __expf(o12[9] - mx);
    float e2 = __expf(o12[10] - mx), e3 = __expf(o12[11] - mx);
    float inv = fast_rcp(e0 + e1 + e2 + e3);
    float wk4[4] = {e0 * inv, e1 * inv, e2 * inv, e3 * inv};
    float xc = (px + 0.5f) * ((float)WC / (float)W) - 0.5f;
    float yc = (py + 0.5f) * ((float)HC / (float)H) - 0.5f;
#pragma unroll
    for (int k = 0; k < 4; ++k) {
        float ix = fminf(fmaxf(xc + 2.0f * tanh_f(o12[2 * k]),     0.0f), (float)(WC - 1));
        float iy = fminf(fmaxf(yc + 2.0f * tanh_f(o12[2 * k + 1]), 0.0f), (float)(HC - 1));
        float x0f = floorf(ix), y0f = floorf(iy);
        int x0 = (int)x0f, y0 = (int)y0f;
        int x1 = min(x0 + 1, WC - 1), y1 = min(y0 + 1, HC - 1);
        float wx = ix - x0f, wy = iy - y0f;
        float wk = wk4[k];
        int lx0 = x0 - wx0, ly0 = y0 - wy0;
        int lx1 = x1 - wx0, ly1 = y1 - wy0;
        zoff[4 * k + 0] = (ly0 * WW + lx0) * PSTR; wgt[4 * k + 0] = (1.0f - wx) * (1.0f - wy) * wk;
        zoff[4 * k + 1] = (ly0 * WW + lx1) * PSTR; wgt[4 * k + 1] = wx * (1.0f - wy) * wk;
        zoff[4 * k + 2] = (ly1 * WW + lx0) * PSTR; wgt[4 * k + 2] = (1.0f - wx) * wy * wk;
        zoff[4 * k + 3] = (ly1 * WW + lx1) * PSTR; wgt[4 * k + 3] = wx * wy * wk;
    }
}

// ---- deform tail: stage coarse window in LDS, gather via ds_read_b128 -----
// Window bound proof: ix = clamp(xc + 2*tanh, 0, WC-1), xc in
// [(ox+0.5)*WC/W - 0.5, (ox+15.5)*WC/W - 0.5] -> x0 in [ox>>SH - 3,
// ox>>SH + 9], x1 <= ox>>SH + 10 (SH=1) / +6 (SH=2) -> WW = 14 / 10.
// Points at 80B stride (r14): bank stride 20 -> alias only at point
// distance 8 (was 2 at 64B). r16's extra swizzle REGRESSED - keep plain.
// LDS: ysum [0,512), zwin [512, 512 + WW*WW*80) <= 16192 < 20736.
// r17: gather in two batches of 8 (same j order -> bit-identical),
// halving peak vv[] liveness to fit the (256,5) 51-VGPR cap.
template<int HC, int WC, int WW, int SH>
static __device__ __forceinline__ void deform_tail(
        const float* o12, int ox, int oy, int px, int py,
        const ushort_t* __restrict__ zb, char* smem,
        float* __restrict__ d, float* __restrict__ dslot,
        int tid, int lane, int wv) {
    float (*ysum)[32] = (float (*)[32])smem;            // [0, 512)
    ushort_t* zwin = (ushort_t*)(smem + 512);           // [512, ...)
    int wx0 = min(max((ox >> SH) - 3, 0), WC - WW);
    int wy0 = min(max((oy >> SH) - 3, 0), HC - WW);

    // local offsets + weights (register work, overlaps staging issue)
    int off[16]; float wg[16];
    calc_off_local<HC, WC, WW>(o12, px, py, wx0, wy0, off, wg);

    // stage the window: WW*WW points x 64 B data in 80 B frames, coalesced
    {
        uint4* zw = (uint4*)(smem + 512);
        const ushort_t* zo = zb + ((size_t)wy0 * WC + wx0) * C;
        for (int i = tid; i < WW * WW * 4; i += 256) {
            int pnt = i >> 2, ch = i & 3;
            int r = pnt / WW, c = pnt - r * WW;
            zw[pnt * 5 + ch] = *(const uint4*)(zo + ((size_t)r * WC + c) * C + ch * 8);
        }
    }
    __syncthreads();

#pragma unroll
    for (int c8 = 0; c8 < 4; ++c8) {
        f32x4 lo = {0.0f, 0.0f, 0.0f, 0.0f};
        f32x4 hi = {0.0f, 0.0f, 0.0f, 0.0f};
#pragma unroll
        for (int h = 0; h < 2; ++h) {
            uint4 vv[8];
#pragma unroll
            for (int j = 0; j < 8; ++j)
                vv[j] = *(const uint4*)(zwin + off[8 * h + j] + c8 * 8);
#pragma unroll
            for (int j = 0; j < 8; ++j) {
                float wj = wg[8 * h + j];
                lo[0] += wj * bl(vv[j].x); lo[1] += wj * bh(vv[j].x);
                lo[2] += wj * bl(vv[j].y); lo[3] += wj * bh(vv[j].y);
                hi[0] += wj * bl(vv[j].z); hi[1] += wj * bh(vv[j].z);
                hi[2] += wj * bl(vv[j].w); hi[3] += wj * bh(vv[j].w);
            }
        }
#pragma unroll
        for (int k = 0; k < 4; ++k) {
            d[(size_t)(c8 * 8 + k) * HW]     = lo[k];
            d[(size_t)(c8 * 8 + 4 + k) * HW] = hi[k];
        }
        // channel means: butterfly-split reduce (10 shuffles for 8 channels)
        float s = red8_ch(lo[0], lo[1], lo[2], lo[3], hi[0], hi[1], hi[2], hi[3], lane);
        if (lane < 8)
            ysum[wv][c8 * 8 + ((lane & 1) * 4 + (lane & 2) + ((lane >> 2) & 1))] = s;
    }
    __syncthreads();
    if (tid < 32) {
        float s = ysum[0][tid] + ysum[1][tid] + ysum[2][tid] + ysum[3][tid];
        atomicAdd(dslot + tid, s * (1.0f / HW));
    }
}

// ---- one head per block (blockIdx.z): MFMA 3x3 conv + LDS-window deform ---
// (256,5) = cap 51; r17 measured VGPR 48, no spill.
__global__ __launch_bounds__(256, 5) void head_deform_kernel(
        const ushort_t* __restrict__ qpad,
        const ushort_t* __restrict__ z1, const ushort_t* __restrict__ z2,
        const ushort_t* __restrict__ w1ra, const ushort_t* __restrict__ w1rb,
        const float* __restrict__ w2a, const float* __restrict__ b2a,
        const float* __restrict__ w2b, const float* __restrict__ b2b,
        float* __restrict__ y1, float* __restrict__ y2, float* __restrict__ dall) {
    __shared__ __align__(16) char smem[TAREA * C * 2];      // 20736 B
    ushort_t* tile = (ushort_t*)smem;
    unsigned* hidw = (unsigned*)smem;                       // bytes [0, 9216)
    int tid = threadIdx.x, b = blockIdx.y, hsel = blockIdx.z;
    int ox = (blockIdx.x & 15) * TILE, oy = (blockIdx.x >> 4) * TILE;
    int lane = tid & 63, wv = tid >> 6;
    int n15 = lane & 15, quad = lane >> 4;
    int tx = tid & 15, ty = tid >> 4;

    // stage q tile (rows contiguous in padded channel-last q)
    {
        const ushort_t* base = qpad + ((size_t)b * WP + oy) * WP * 32;
        uint4* tl = (uint4*)tile;
        for (int i = tid; i < 1296; i += 256) {      // 18 rows * 72 16B-chunks
            int yy = i / 72, r = i - yy * 72;
            tl[i] = *(const uint4*)(base + ((size_t)yy * WP + ox) * 32 + r * 8);
        }
    }
    __syncthreads();

    const ushort_t* w1r = hsel ? w1rb : w1ra;
    bf16x8 af[9];
#pragma unroll
    for (int j = 0; j < 9; ++j)
        af[j] = *(const bf16x8*)(w1r + n15 * 288 + j * 32 + quad * 8);
    unsigned pk[8];
#pragma unroll
    for (int g = 0; g < 4; ++g) {
        int yrow = wv * 4 + g;
        f32x4 acc = {0.0f, 0.0f, 0.0f, 0.0f};
#pragma unroll
        for (int jy = 0; jy < 3; ++jy)
#pragma unroll
            for (int jx = 0; jx < 3; ++jx) {
                const bf16x8* bp = (const bf16x8*)(tile +
                    ((yrow + jy) * HALO + n15 + jx) * 32 + quad * 8);
                acc = __builtin_amdgcn_mfma_f32_16x16x32_bf16(
                    af[jy * 3 + jx], *bp, acc, 0, 0, 0);
            }
        pk[2 * g]     = (unsigned)f2b(acc[0]) | ((unsigned)f2b(acc[1]) << 16);
        pk[2 * g + 1] = (unsigned)f2b(acc[2]) | ((unsigned)f2b(acc[3]) << 16);
    }
    __syncthreads();   // ALL waves done reading tile before hidw overwrites it
#pragma unroll
    for (int g = 0; g < 4; ++g) {
        int pxl = (wv * 4 + g) * 16 + n15;
        hidw[pxl * 9 + quad * 2]     = pk[2 * g];
        hidw[pxl * 9 + quad * 2 + 1] = pk[2 * g + 1];
    }
    // hidw write->read is same-wave (pxl in [wv*64, wv*64+64)); lgkmcnt covers it
    float hid[CH];
#pragma unroll
    for (int j = 0; j < 8; ++j) {
        unsigned u = hidw[tid * 9 + j];
        hid[2 * j]     = silu_f(bl(u));
        hid[2 * j + 1] = silu_f(bh(u));
    }

    // ---- tail for this head ----
    const float* w2 = hsel ? w2b : w2a;
    const float* bs = hsel ? b2b : b2a;
    float o12[CO];
#pragma unroll
    for (int j = 0; j < CO; ++j) {
        float a = bs[j];
#pragma unroll
        for (int i = 0; i < CH; ++i) a += w2[j * CH + i] * hid[i];
        o12[j] = a;
    }
    __syncthreads();   // all waves done reading hidw; zwin may overwrite it

    int px = ox + tx, py = oy + ty;
    int p = py * W + px;
    if (hsel == 0)
        deform_tail<H1, W1, 14, 1>(o12, ox, oy, px, py,
            z1 + (size_t)b * HW1 * C, smem,
            y1 + (size_t)b * C * HW + p, dall + b * 96 + 32, tid, lane, wv);
    else
        deform_tail<H2, W2, 10, 2>(o12, ox, oy, px, py,
            z2 + (size_t)b * HW2 * C, smem,
            y2 + (size_t)b * C * HW + p, dall + b * 96 + 64, tid, lane, wv);
}

// ---- fused gate (alpha recompute per block) + mix + 1x1 conv + residual ---
__global__ __launch_bounds__(256, 4) void final_kernel(
        const float* __restrict__ x,
        const float* __restrict__ z0, const float* __restrict__ y1,
        const float* __restrict__ y2, const float* __restrict__ dall,
        const float* __restrict__ rw1, const float* __restrict__ rb1,
        const float* __restrict__ rw2, const float* __restrict__ rb2,
        const float* __restrict__ fw, float* __restrict__ out) {
    __shared__ float ws[C * C];
    __shared__ float hid[32];
    __shared__ float a3[3];
    int tid = threadIdx.x;
    int idx = blockIdx.x * blockDim.x + tid;
    int b = idx / HW, p = idx - b * HW;
    for (int i = tid; i < C * C; i += blockDim.x) ws[i] = fw[i];
    if (tid < 32) {
        float a = rb1[tid];
        for (int k = 0; k < 96; ++k) a += dall[b * 96 + k] * rw1[k * 32 + tid];
        hid[tid] = silu_f(a);
    }
    __syncthreads();
    if (tid == 0) {
        float lg[3];
#pragma unroll
        for (int t = 0; t < 3; ++t) {
            float acc = rb2[t];
            for (int jj = 0; jj < 32; ++jj) acc += hid[jj] * rw2[jj * 3 + t];
            lg[t] = acc;
        }
        float mx = fmaxf(lg[0], fmaxf(lg[1], lg[2]));
        float e0 = __expf(lg[0] - mx), e1 = __expf(lg[1] - mx), e2 = __expf(lg[2] - mx);
        float inv = fast_rcp(e0 + e1 + e2);
        a3[0] = e0 * inv; a3[1] = e1 * inv; a3[2] = e2 * inv;
    }
    __syncthreads();
    float a0 = a3[0], a1 = a3[1], a2 = a3[2];
    size_t base = (size_t)b * C * HW + p;
    float mix[C];
#pragma unroll
    for (int i = 0; i < C; ++i) {
        size_t e = base + (size_t)i * HW;
        mix[i] = a0 * z0[e] + a1 * y1[e] + a2 * y2[e];
    }
#pragma unroll 4
    for (int o = 0; o < C; ++o) {
        float acc = 0.0f;
#pragma unroll
        for (int i = 0; i < C; ++i) acc += ws[o * C + i] * mix[i];
        size_t e = base + (size_t)o * HW;
        out[e] = acc + x[e];
    }
}

// ---------------------------------------------------------------------------
extern "C" void kernel_launch(void* const* d_in, const int* in_sizes, int n_in,
                              void* d_out, int out_size, void* d_ws, size_t ws_size,
                              hipStream_t stream) {
    const float* x       = (const float*)d_in[0];
    const float* ds_dw[3] = {(const float*)d_in[1],  (const float*)d_in[7],  (const float*)d_in[13]};
    const float* ds_pw[3] = {(const float*)d_in[2],  (const float*)d_in[8],  (const float*)d_in[14]};
    const float* ds_g[3]  = {(const float*)d_in[3],  (const float*)d_in[9],  (const float*)d_in[15]};
    const float* ds_b[3]  = {(const float*)d_in[4],  (const float*)d_in[10], (const float*)d_in[16]};
    const float* ds_m[3]  = {(const float*)d_in[5],  (const float*)d_in[11], (const float*)d_in[17]};
    const float* ds_v[3]  = {(const float*)d_in[6],  (const float*)d_in[12], (const float*)d_in[18]};
    const float* qproj_w = (const float*)d_in[19];
    const float* h1_w1   = (const float*)d_in[20];
    const float* h1_w2   = (const float*)d_in[21];
    const float* h1_b2   = (const float*)d_in[22];
    const float* h2_w1   = (const float*)d_in[23];
    const float* h2_w2   = (const float*)d_in[24];
    const float* h2_b2   = (const float*)d_in[25];
    const float* r_w1    = (const float*)d_in[26];
    const float* r_b1    = (const float*)d_in[27];
    const float* r_w2    = (const float*)d_in[28];
    const float* r_b2    = (const float*)d_in[29];
    const float* final_w = (const float*)d_in[30];
    float* out = (float*)d_out;

    constexpr size_t N0 = (size_t)B * C * HW;
    constexpr size_t N1 = (size_t)B * C * HW1;
    constexpr size_t N2 = (size_t)B * C * HW2;
    constexpr size_t NQ = ((size_t)B * WP * WP * 32 + 1) / 2;   // qpad (u16) in floats

    float* w = (float*)d_ws;
    float* z0   = w; w += N0;      // plane fp32
    float* y1   = w; w += N0;      // plane fp32
    float* y2   = w; w += N0;      // plane fp32
    ushort_t* z1cl = (ushort_t*)w; w += N1 / 2;   // bf16 channel-last
    ushort_t* z2cl = (ushort_t*)w; w += N2 / 2;   // bf16 channel-last
    float* s1   = w; w += N1;
    ushort_t* qpad = (ushort_t*)w; w += NQ;
    ushort_t* w1ra = (ushort_t*)w; w += 2304;   // 4608 bf16
    ushort_t* w1rb = (ushort_t*)w; w += 2304;
    ushort_t* pwr  = (ushort_t*)w; w += 2048;   // 4096 bf16: pw0,pw1,pw2,qw
    float* dall  = w; w += 512;
    (void)ws_size; (void)in_sizes; (void)n_in; (void)out_size;

    const int T = 256;
    auto g = [](size_t n, int t) { return (int)((n + t - 1) / t); };

    pre_kernel<<<g(N1 + 4112 + 512 + 4608 + 4608 + 4096, T), T, 0, stream>>>(
        x, s1, qpad, dall, h1_w1, h2_w1, w1ra, w1rb,
        ds_pw[0], ds_pw[1], ds_pw[2], qproj_w, pwr);

    DsParams p0 = {ds_dw[0], ds_g[0], ds_b[0], ds_m[0], ds_v[0]};
    DsParams p1 = {ds_dw[1], ds_g[1], ds_b[1], ds_m[1], ds_v[1]};
    DsParams p2 = {ds_dw[2], ds_g[2], ds_b[2], ds_m[2], ds_v[2]};
    fused_ds_all_kernel<<<1344, T, 0, stream>>>(
        x, s1, p0, p1, p2, pwr, z0, z1cl, z2cl, qpad, dall);

    head_deform_kernel<<<dim3((H / TILE) * (W / TILE), B, 2), T, 0, stream>>>(
        qpad, z1cl, z2cl, w1ra, w1rb, h1_w2, h1_b2, h2_w2, h2_b2, y1, y2, dall);

    final_kernel<<<g((size_t)B * HW, T), T, 0, stream>>>(
        x, z0, y1, y2, dall, r_w1, r_b1, r_w2, r_b2, final_w, out);
}